// Round 1
// baseline (35542.599 us; speedup 1.0000x reference)
//
#include <hip/hip_runtime.h>
#include <hip/hip_bf16.h>

// LSTM T=2048, B=64, I=256, H=512 — persistent single-kernel scan, f32 I/O.
// v2: 32 blocks x 256 threads (was 128x128). Block = one 16-col h group (ng);
// waves = (row-pair mp, gate-pair gp); each wave computes two 16-row M tiles
// with shared weight fragments. Barrier: per-block release flag (128 B apart)
// + one wave spinning on all 32 flags in parallel — removes the 128-way
// same-line atomic serialization. out/h stores nontemporal + issued after the
// release so the per-step buffer_wbl2 writeback payload is ~empty.
// h-part weights (k<512) persist in VGPRs (128/thread); x-part weights in LDS.

#define T_STEPS 2048
#define BATCH   64
#define IN_F    256
#define HID     512
#define KTOT    768          // H + I, concat order (h, x)
#define BHSZ    (BATCH*HID)  // 32768
#define NBLK    32
#define NTHR    256
#define FSTR    32           // flag stride in u32 (128 B padding)

typedef __attribute__((ext_vector_type(8))) short  short8;  // 8 bf16 = 4 VGPRs
typedef __attribute__((ext_vector_type(4))) float  f32x4;
typedef __attribute__((ext_vector_type(2))) float  f32x2;

__device__ __forceinline__ f32x4 mfma16(short8 a, short8 b, f32x4 c) {
    return __builtin_amdgcn_mfma_f32_16x16x32_bf16(a, b, c, 0, 0, 0);
}
__device__ __forceinline__ short bf16bits(float f) {
    return (short)__builtin_bit_cast(unsigned short, __float2bfloat16(f));
}
__device__ __forceinline__ short8 cvt8(const float* __restrict__ p) {
    f32x4 a = *(const f32x4*)p;
    f32x4 b = *(const f32x4*)(p + 4);
    short8 r;
    r[0] = bf16bits(a[0]); r[1] = bf16bits(a[1]); r[2] = bf16bits(a[2]); r[3] = bf16bits(a[3]);
    r[4] = bf16bits(b[0]); r[5] = bf16bits(b[1]); r[6] = bf16bits(b[2]); r[7] = bf16bits(b[3]);
    return r;
}
__device__ __forceinline__ float sigf(float x)      { return 1.f / (1.f + __expf(-x)); }
__device__ __forceinline__ float tanh_fast(float x) { return 2.f / (1.f + __expf(-2.f * x)) - 1.f; }

__global__ void __launch_bounds__(NTHR, 1)
lstm_persistent(const float* __restrict__ x,
                const float* __restrict__ Wf, const float* __restrict__ bfv,
                const float* __restrict__ Wi, const float* __restrict__ biv,
                const float* __restrict__ Wc, const float* __restrict__ bcv,
                const float* __restrict__ Wo, const float* __restrict__ bov,
                float* __restrict__ out, unsigned* flags, short* hping)
{
    const int tid  = threadIdx.x;
    const int w    = tid >> 6;
    const int gp   = w & 1;          // 0: f,i   1: c~,o
    const int mp   = w >> 1;         // row-pair: rows mp*32 .. mp*32+31
    const int m0   = mp << 5;
    const int lane = tid & 63;
    const int bn   = lane & 15;      // A-row / B-col / C-col within the 16-tile
    const int quad = lane >> 4;
    const int ng   = blockIdx.x;     // h-col group (0..31)
    const int hbase = ng << 4;

    __shared__ short8 wx[2][2][8][64];   // x-part weights [gp][gate][kt][lane] = 32 KB
    __shared__ float  glds[4][64][17];   // gate preacts f,i,c~,o (padded stride 17)

    // ---- preload: h-part B fragments f32 -> bf16, persist in VGPRs all 2048 steps ----
    // B[k][n] = W[row = hbase+n][k]; lane n=bn reads 8 contiguous k at k = kt*32 + quad*8.
    const float* Wa = gp ? Wc : Wf;
    const float* Wb = gp ? Wo : Wi;
    short8 Ba[16], Bb[16];
    {
        const float* ra = Wa + (size_t)(hbase + bn) * KTOT + quad * 8;
        const float* rb = Wb + (size_t)(hbase + bn) * KTOT + quad * 8;
        #pragma unroll
        for (int kt = 0; kt < 16; ++kt) {
            Ba[kt] = cvt8(ra + kt * 32);
            Bb[kt] = cvt8(rb + kt * 32);
        }
        if (mp == 0) {   // waves 0,1 stage x-part weights (k >= 512) to LDS
            #pragma unroll
            for (int kt = 0; kt < 8; ++kt) {
                wx[gp][0][kt][lane] = cvt8(ra + 512 + kt * 32);
                wx[gp][1][kt][lane] = cvt8(rb + 512 + kt * 32);
            }
        }
    }

    // ---- epilogue cell ownership: thread -> rows (er, er+32) x cols (ec, ec+1) ----
    const int er = tid >> 3;             // 0..31
    const int ec = (tid & 7) << 1;       // even col in 0..14
    const f32x2 vbf = *(const f32x2*)(bfv + hbase + ec);
    const f32x2 vbi = *(const f32x2*)(biv + hbase + ec);
    const f32x2 vbc = *(const f32x2*)(bcv + hbase + ec);
    const f32x2 vbo = *(const f32x2*)(bov + hbase + ec);
    float c00 = 0.f, c01 = 0.f, c10 = 0.f, c11 = 0.f;

    __syncthreads();   // wx ready

    #pragma unroll 1
    for (int t = 0; t < T_STEPS; ++t) {
        f32x4 z = {0.f, 0.f, 0.f, 0.f};
        f32x4 aA0 = z, aA0b = z, aB0 = z, aB0b = z;   // M-tile 0 (rows m0..m0+15)
        f32x4 aA1 = z, aA1b = z, aB1 = z, aB1b = z;   // M-tile 1 (rows m0+16..m0+31)

        // x-part first: independent of h_{t-1}, overlaps other blocks' step tails.
        {
            const float* xr0 = x + ((size_t)t * BATCH + m0 + bn) * IN_F + quad * 8;
            const float* xr1 = xr0 + 16 * IN_F;
            #pragma unroll
            for (int kt = 0; kt < 8; ++kt) {
                short8 wa = wx[gp][0][kt][lane];
                short8 wb = wx[gp][1][kt][lane];
                short8 a0 = cvt8(xr0 + kt * 32);
                short8 a1 = cvt8(xr1 + kt * 32);
                if (kt & 1) { aA0b = mfma16(a0, wa, aA0b); aB0b = mfma16(a0, wb, aB0b);
                              aA1b = mfma16(a1, wa, aA1b); aB1b = mfma16(a1, wb, aB1b); }
                else        { aA0  = mfma16(a0, wa, aA0 ); aB0  = mfma16(a0, wb, aB0 );
                              aA1  = mfma16(a1, wa, aA1 ); aB1  = mfma16(a1, wb, aB1 ); }
            }
        }

        if (t > 0) {
            // wait until all NBLK blocks published h_{t-1}: parallel flag scan
            if (tid < 64) {
                const unsigned tgt = (unsigned)t;
                const unsigned* fp = flags + (size_t)(tid & 31) * FSTR;
                while (__hip_atomic_load(fp, __ATOMIC_RELAXED, __HIP_MEMORY_SCOPE_AGENT) < tgt)
                    __builtin_amdgcn_s_sleep(1);
                __builtin_amdgcn_fence(__ATOMIC_ACQUIRE, "agent");  // invalidate stale cache
            }
            __syncthreads();
            const short* hr0 = hping + (size_t)((t - 1) & 1) * BHSZ + (size_t)(m0 + bn) * HID + quad * 8;
            const short* hr1 = hr0 + 16 * HID;
            #pragma unroll
            for (int kt = 0; kt < 16; ++kt) {
                short8 a0 = *(const short8*)(hr0 + kt * 32);
                short8 a1 = *(const short8*)(hr1 + kt * 32);
                if (kt & 1) { aA0b = mfma16(a0, Ba[kt], aA0b); aB0b = mfma16(a0, Bb[kt], aB0b);
                              aA1b = mfma16(a1, Ba[kt], aA1b); aB1b = mfma16(a1, Bb[kt], aB1b); }
                else        { aA0  = mfma16(a0, Ba[kt], aA0 ); aB0  = mfma16(a0, Bb[kt], aB0 );
                              aA1  = mfma16(a1, Ba[kt], aA1 ); aB1  = mfma16(a1, Bb[kt], aB1 ); }
            }
        }
        aA0 += aA0b; aB0 += aB0b; aA1 += aA1b; aB1 += aB1b;

        // C/D layout (verified m89): col = lane&15, row = quad*4 + reg
        {
            const int wr = m0 + quad * 4;
            #pragma unroll
            for (int r = 0; r < 4; ++r) {
                glds[gp * 2 + 0][wr + r][bn]      = aA0[r];
                glds[gp * 2 + 1][wr + r][bn]      = aB0[r];
                glds[gp * 2 + 0][wr + 16 + r][bn] = aA1[r];
                glds[gp * 2 + 1][wr + 16 + r][bn] = aB1[r];
            }
        }
        __syncthreads();

        // elementwise LSTM cell, fp32; 2 rows x 2 cols per thread
        const float f0 = sigf(glds[0][er][ec]      + vbf.x);
        const float f1 = sigf(glds[0][er][ec + 1]  + vbf.y);
        const float i0 = sigf(glds[1][er][ec]      + vbi.x);
        const float i1 = sigf(glds[1][er][ec + 1]  + vbi.y);
        const float g0 = tanh_fast(glds[2][er][ec]     + vbc.x);
        const float g1 = tanh_fast(glds[2][er][ec + 1] + vbc.y);
        const float o0 = sigf(glds[3][er][ec]      + vbo.x);
        const float o1 = sigf(glds[3][er][ec + 1]  + vbo.y);
        c00 = f0 * c00 + i0 * g0;  const float h00 = o0 * tanh_fast(c00);
        c01 = f1 * c01 + i1 * g1;  const float h01 = o1 * tanh_fast(c01);

        const float F0 = sigf(glds[0][er + 32][ec]      + vbf.x);
        const float F1 = sigf(glds[0][er + 32][ec + 1]  + vbf.y);
        const float I0 = sigf(glds[1][er + 32][ec]      + vbi.x);
        const float I1 = sigf(glds[1][er + 32][ec + 1]  + vbi.y);
        const float G0 = tanh_fast(glds[2][er + 32][ec]     + vbc.x);
        const float G1 = tanh_fast(glds[2][er + 32][ec + 1] + vbc.y);
        const float O0 = sigf(glds[3][er + 32][ec]      + vbo.x);
        const float O1 = sigf(glds[3][er + 32][ec + 1]  + vbo.y);
        c10 = F0 * c10 + I0 * G0;  const float h10 = O0 * tanh_fast(c10);
        c11 = F1 * c11 + I1 * G1;  const float h11 = O1 * tanh_fast(c11);

        // bf16 h to ws ping-pong (packed u32, nontemporal -> lands at LLC, wbl2 stays cheap)
        {
            short* hw = hping + (size_t)(t & 1) * BHSZ + (size_t)er * HID + hbase + ec;
            const unsigned hp0 = (unsigned)(unsigned short)bf16bits(h00)
                               | ((unsigned)(unsigned short)bf16bits(h01) << 16);
            const unsigned hp1 = (unsigned)(unsigned short)bf16bits(h10)
                               | ((unsigned)(unsigned short)bf16bits(h11) << 16);
            __builtin_nontemporal_store(hp0, (unsigned*)hw);
            __builtin_nontemporal_store(hp1, (unsigned*)(hw + 32 * HID));
        }

        __syncthreads();  // drains vmcnt: all h-stores done + glds reads finished
        if (tid == 0)
            __hip_atomic_store(flags + (size_t)blockIdx.x * FSTR, (unsigned)(t + 1),
                               __ATOMIC_RELEASE, __HIP_MEMORY_SCOPE_AGENT);

        // f32 h to d_out AFTER the release: off the critical path, nontemporal
        {
            const size_t ob = (size_t)t * BHSZ + (size_t)er * HID + hbase + ec;
            f32x2 v0 = {h00, h01}, v1 = {h10, h11};
            __builtin_nontemporal_store(v0, (f32x2*)(out + ob));
            __builtin_nontemporal_store(v1, (f32x2*)(out + ob + 32 * HID));
            if (t == T_STEPS - 1) {  // h_last
                const size_t ol = (size_t)T_STEPS * BHSZ + (size_t)er * HID + hbase + ec;
                __builtin_nontemporal_store(v0, (f32x2*)(out + ol));
                __builtin_nontemporal_store(v1, (f32x2*)(out + ol + 32 * HID));
            }
        }
    }

    // c_last
    {
        const size_t oc = (size_t)T_STEPS * BHSZ + BHSZ + (size_t)er * HID + hbase + ec;
        f32x2 v0 = {c00, c01}, v1 = {c10, c11};
        __builtin_nontemporal_store(v0, (f32x2*)(out + oc));
        __builtin_nontemporal_store(v1, (f32x2*)(out + oc + 32 * HID));
    }
}

extern "C" void kernel_launch(void* const* d_in, const int* in_sizes, int n_in,
                              void* d_out, int out_size, void* d_ws, size_t ws_size,
                              hipStream_t stream) {
    // ws layout: [0, 4096) per-block flags (32 x 128 B); [4096, 4096 + 2*B*H*2) bf16 h ping-pong
    hipMemsetAsync(d_ws, 0, 4096, stream);
    unsigned* flags = (unsigned*)d_ws;
    short*    hping = (short*)((char*)d_ws + 4096);
    lstm_persistent<<<NBLK, NTHR, 0, stream>>>(
        (const float*)d_in[0],
        (const float*)d_in[1], (const float*)d_in[2],
        (const float*)d_in[3], (const float*)d_in[4],
        (const float*)d_in[5], (const float*)d_in[6],
        (const float*)d_in[7], (const float*)d_in[8],
        (float*)d_out, flags, hping);
}

// Round 2
// 20596.381 us; speedup vs baseline: 1.7257x; 1.7257x over previous
//
#include <hip/hip_runtime.h>
#include <hip/hip_bf16.h>

// LSTM T=2048, B=64, I=256, H=512 — persistent single-kernel scan, f32 I/O.
// v3 = v1 geometry (128 blocks x 128 threads, proven 18.7 ms) with ONE delta set:
//  (a) barrier = per-block release FLAG (128 B apart) + parallel scan — no 128-way
//      same-line atomic RMW serialization;
//  (b) sync domain shrunk 4x: block (mg,ng) reads only h rows 16mg..16mg+15, which
//      are produced by blocks (mg, 0..31) — so it waits on those 32 flags only;
//  (c) f32 out stores issued AFTER the flag release (off the critical path).
// NO nontemporal stores (v2 lesson: nt h stores bypassed LLC -> +810 MB HBM fetch
// and ~2x regression). h stays dirty-in-L2 -> release wbl2 -> LLC -> consumers.

#define T_STEPS 2048
#define BATCH   64
#define IN_F    256
#define HID     512
#define KTOT    768          // H + I, concat order (h, x)
#define BHSZ    (BATCH*HID)  // 32768
#define NBLK    128
#define FSTR    32           // flag stride in u32 (128 B padding)

typedef __attribute__((ext_vector_type(8))) short  short8;  // 8 bf16 = 4 VGPRs
typedef __attribute__((ext_vector_type(4))) float  f32x4;

__device__ __forceinline__ f32x4 mfma16(short8 a, short8 b, f32x4 c) {
    return __builtin_amdgcn_mfma_f32_16x16x32_bf16(a, b, c, 0, 0, 0);
}
__device__ __forceinline__ short bf16bits(float f) {
    return (short)__builtin_bit_cast(unsigned short, __float2bfloat16(f));
}
__device__ __forceinline__ short8 cvt8(const float* __restrict__ p) {
    f32x4 a = *(const f32x4*)p;
    f32x4 b = *(const f32x4*)(p + 4);
    short8 r;
    r[0] = bf16bits(a[0]); r[1] = bf16bits(a[1]); r[2] = bf16bits(a[2]); r[3] = bf16bits(a[3]);
    r[4] = bf16bits(b[0]); r[5] = bf16bits(b[1]); r[6] = bf16bits(b[2]); r[7] = bf16bits(b[3]);
    return r;
}
__device__ __forceinline__ float sigf(float x)      { return 1.f / (1.f + __expf(-x)); }
__device__ __forceinline__ float tanh_fast(float x) { return 2.f / (1.f + __expf(-2.f * x)) - 1.f; }

__global__ void __launch_bounds__(128, 1)
lstm_persistent(const float* __restrict__ x,
                const float* __restrict__ Wf, const float* __restrict__ bfv,
                const float* __restrict__ Wi, const float* __restrict__ biv,
                const float* __restrict__ Wc, const float* __restrict__ bcv,
                const float* __restrict__ Wo, const float* __restrict__ bov,
                float* __restrict__ out, unsigned* flags, short* hping)
{
    const int tid  = threadIdx.x;
    const int wv   = tid >> 6;        // wave 0: f,i   wave 1: c~,o
    const int lane = tid & 63;
    const int bn   = lane & 15;       // A-row / B-col / C-col within the 16-tile
    const int quad = lane >> 4;
    const int mg   = blockIdx.x & 3;  // batch-row group (sync domain)
    const int ng   = blockIdx.x >> 2; // h-col group (0..31)
    const int hbase = ng << 4;
    const int m0    = mg << 4;

    // ---- preload B fragments (weights) f32 -> bf16, persist in VGPRs all 2048 steps ----
    // B[k][n] = W[row = hbase+n][k]; lane n=bn reads 8 contiguous k at k = kt*32 + quad*8.
    short8 Ba[24], Bb[24];
    {
        const float* ra = (wv ? Wc : Wf) + (size_t)(hbase + bn) * KTOT + quad * 8;
        const float* rb = (wv ? Wo : Wi) + (size_t)(hbase + bn) * KTOT + quad * 8;
        #pragma unroll
        for (int kt = 0; kt < 24; ++kt) {
            Ba[kt] = cvt8(ra + kt * 32);
            Bb[kt] = cvt8(rb + kt * 32);
        }
    }

    // ---- epilogue cell ownership: thread -> (rows er, er+8) x (col ec); c in fp32 regs ----
    const int ec = tid & 15;
    const int er = tid >> 4;          // 0..7
    const float vbf = bfv[hbase + ec];
    const float vbi = biv[hbase + ec];
    const float vbc = bcv[hbase + ec];
    const float vbo = bov[hbase + ec];
    float c0 = 0.f, c1 = 0.f;

    __shared__ float glds[4][16][17];  // gate preacts f,i,c~,o (padded stride 17)

    #pragma unroll 1
    for (int t = 0; t < T_STEPS; ++t) {
        f32x4 aA = {0.f,0.f,0.f,0.f}, aA2 = aA, aB = aA, aB2 = aA;

        // x-part first: independent of h_{t-1}, overlaps the barrier spin below.
        {
            const float* xr = x + ((size_t)t * BATCH + m0 + bn) * IN_F + quad * 8;
            #pragma unroll
            for (int kt = 0; kt < 8; ++kt) {
                short8 av = cvt8(xr + kt * 32);
                if (kt & 1) { aA2 = mfma16(av, Ba[16 + kt], aA2); aB2 = mfma16(av, Bb[16 + kt], aB2); }
                else        { aA  = mfma16(av, Ba[16 + kt], aA ); aB  = mfma16(av, Bb[16 + kt], aB ); }
            }
        }

        if (t > 0) {
            // wait until the 32 blocks of this mg-domain published h_{t-1}:
            // lane l (< 32) watches block (mg, ng'=l) at flag index (l*4 + mg).
            if (tid < 32) {
                const unsigned tgt = (unsigned)t;
                const unsigned* fp = flags + (size_t)((tid << 2) + mg) * FSTR;
                while (__hip_atomic_load(fp, __ATOMIC_RELAXED, __HIP_MEMORY_SCOPE_AGENT) < tgt)
                    __builtin_amdgcn_s_sleep(1);
                __builtin_amdgcn_fence(__ATOMIC_ACQUIRE, "agent");  // invalidate stale cache
            }
            __syncthreads();
            const short* hr = hping + (size_t)((t - 1) & 1) * BHSZ + (m0 + bn) * HID + quad * 8;
            #pragma unroll
            for (int kt = 0; kt < 16; ++kt) {
                short8 av = *(const short8*)(hr + kt * 32);
                if (kt & 1) { aA2 = mfma16(av, Ba[kt], aA2); aB2 = mfma16(av, Bb[kt], aB2); }
                else        { aA  = mfma16(av, Ba[kt], aA ); aB  = mfma16(av, Bb[kt], aB ); }
            }
        }
        aA += aA2; aB += aB2;

        // C/D layout (verified m89): col = lane&15, row = quad*4 + reg
        #pragma unroll
        for (int r = 0; r < 4; ++r) {
            glds[wv * 2 + 0][quad * 4 + r][bn] = aA[r];
            glds[wv * 2 + 1][quad * 4 + r][bn] = aB[r];
        }
        __syncthreads();

        // elementwise LSTM cell, fp32; two (row, col) cells per thread
        const float f0 = sigf(glds[0][er][ec] + vbf);
        const float i0 = sigf(glds[1][er][ec] + vbi);
        const float g0 = tanh_fast(glds[2][er][ec] + vbc);
        const float o0 = sigf(glds[3][er][ec] + vbo);
        c0 = f0 * c0 + i0 * g0;
        const float h0 = o0 * tanh_fast(c0);

        const float f1 = sigf(glds[0][er + 8][ec] + vbf);
        const float i1 = sigf(glds[1][er + 8][ec] + vbi);
        const float g1 = tanh_fast(glds[2][er + 8][ec] + vbc);
        const float o1 = sigf(glds[3][er + 8][ec] + vbo);
        c1 = f1 * c1 + i1 * g1;
        const float h1 = o1 * tanh_fast(c1);

        // bf16 h to ws ping-pong for next step's MFMA A-operand (regular store:
        // stays dirty in L2, release wbl2 pushes it to LLC for consumers)
        short* hw = hping + (size_t)(t & 1) * BHSZ + (size_t)(m0 + er) * HID + hbase + ec;
        hw[0]       = bf16bits(h0);
        hw[8 * HID] = bf16bits(h1);

        __syncthreads();  // all waves' h-stores issued + glds reads done
        if (tid == 0)
            __hip_atomic_store(flags + (size_t)blockIdx.x * FSTR, (unsigned)(t + 1),
                               __ATOMIC_RELEASE, __HIP_MEMORY_SCOPE_AGENT);

        // f32 h to d_out AFTER the release — off the recurrence critical path.
        {
            const size_t ob = (size_t)t * BHSZ + (size_t)(m0 + er) * HID + hbase + ec;
            out[ob]           = h0;
            out[ob + 8 * HID] = h1;
            if (t == T_STEPS - 1) {  // h_last
                const size_t ol = (size_t)T_STEPS * BHSZ + (size_t)(m0 + er) * HID + hbase + ec;
                out[ol]           = h0;
                out[ol + 8 * HID] = h1;
            }
        }
    }

    // c_last
    const size_t oc = (size_t)T_STEPS * BHSZ + BHSZ + (size_t)(m0 + er) * HID + hbase + ec;
    out[oc]           = c0;
    out[oc + 8 * HID] = c1;
}

extern "C" void kernel_launch(void* const* d_in, const int* in_sizes, int n_in,
                              void* d_out, int out_size, void* d_ws, size_t ws_size,
                              hipStream_t stream) {
    // ws layout: [0, 16384) per-block flags (128 x 128 B); [16384, +2*B*H*2) bf16 h ping-pong
    hipMemsetAsync(d_ws, 0, 16384, stream);
    unsigned* flags = (unsigned*)d_ws;
    short*    hping = (short*)((char*)d_ws + 16384);
    lstm_persistent<<<NBLK, 128, 0, stream>>>(
        (const float*)d_in[0],
        (const float*)d_in[1], (const float*)d_in[2],
        (const float*)d_in[3], (const float*)d_in[4],
        (const float*)d_in[5], (const float*)d_in[6],
        (const float*)d_in[7], (const float*)d_in[8],
        (float*)d_out, flags, hping);
}